// Round 1
// baseline (935.016 us; speedup 1.0000x reference)
//
#include <hip/hip_runtime.h>
#include <stdint.h>
#include <stddef.h>

// ScaledDotProductAttention: B=64, Lq=Lk=2048, D=64, fp32 in/out.
// out tuple = (output [64][2048][64], attn [64][2048][2048]) concat in d_out.
// Strategy: bf16 MFMA for QK^T and PV; fp32 logits staged in LDS (128KB/WG);
// single HBM read of mask, single HBM write of attn (memory-roofline 2.27GB).
// d_ws usage: 48 MB for bf16 Q, bf16 K, bf16 V^T (pre-pass kernels).

typedef __attribute__((ext_vector_type(4))) float f32x4;
typedef __attribute__((ext_vector_type(8))) short short8;
typedef __attribute__((ext_vector_type(4))) unsigned short ushort4v;
typedef __attribute__((ext_vector_type(8))) unsigned short ushort8v;

static constexpr int BATCH = 64;
static constexpr int SEQ   = 2048;   // lq == lk
static constexpr int HD    = 64;     // head dim
static constexpr int QB    = 16;     // q rows per workgroup
static constexpr float NEG = -1e30f;

__device__ __forceinline__ unsigned short f2bf(float f) {
  // round-to-nearest-even fp32 -> bf16
  unsigned int u = __builtin_bit_cast(unsigned int, f);
  u += 0x7fffu + ((u >> 16) & 1u);
  return (unsigned short)(u >> 16);
}

// ---------------- pre-pass: fp32 -> bf16 flat convert ----------------
__global__ void cvt_bf16_kernel(const float* __restrict__ in,
                                unsigned short* __restrict__ out, int n4) {
  int i = blockIdx.x * blockDim.x + threadIdx.x;
  if (i >= n4) return;
  f32x4 v = *(const f32x4*)(in + (size_t)i * 4);
  ushort4v o;
  o[0] = f2bf(v[0]); o[1] = f2bf(v[1]); o[2] = f2bf(v[2]); o[3] = f2bf(v[3]);
  *(ushort4v*)(out + (size_t)i * 4) = o;
}

// ---------------- pre-pass: V [b][k][d] -> VT bf16 [b][d][k] ----------------
__global__ void vtrans_kernel(const float* __restrict__ v,
                              unsigned short* __restrict__ vt) {
  __shared__ float tile[64][65];
  const int b  = blockIdx.x >> 5;
  const int k0 = (blockIdx.x & 31) << 6;
  const int t  = threadIdx.x;
  const int kk = t >> 4;
  const int d4 = (t & 15) << 2;
#pragma unroll
  for (int i = 0; i < 4; ++i) {
    f32x4 val = *(const f32x4*)(v + ((size_t)(b * SEQ + k0 + kk + 16 * i)) * HD + d4);
    tile[kk + 16 * i][d4 + 0] = val[0];
    tile[kk + 16 * i][d4 + 1] = val[1];
    tile[kk + 16 * i][d4 + 2] = val[2];
    tile[kk + 16 * i][d4 + 3] = val[3];
  }
  __syncthreads();
  const int d  = t >> 2;
  const int ks = (t & 3) << 4;
  ushort8v o0, o1;
#pragma unroll
  for (int j = 0; j < 8; ++j) o0[j] = f2bf(tile[ks + j][d]);
#pragma unroll
  for (int j = 0; j < 8; ++j) o1[j] = f2bf(tile[ks + 8 + j][d]);
  unsigned short* dst = vt + ((size_t)(b * HD + d)) * SEQ + k0 + ks;
  *(ushort8v*)(dst)     = o0;
  *(ushort8v*)(dst + 8) = o1;
}

// ---------------- main fused attention ----------------
// grid: 64 batches x 128 q-tiles; block: 256 thr (4 waves, wave w owns k-range
// [w*512, w*512+512)). LDS: per-wave 16x512 fp32 logits, XOR-swizzled.
__global__ __launch_bounds__(256, 1) void attn_kernel(
    const unsigned short* __restrict__ qb,
    const unsigned short* __restrict__ kb,
    const unsigned short* __restrict__ vt,
    const float* __restrict__ mask,
    float* __restrict__ out,
    float* __restrict__ attn) {
  __shared__ float s_lds[4 * QB * 512];  // 131072 B
  __shared__ float stat_m[4][16];
  __shared__ float stat_l[4][16];

  const int tid  = threadIdx.x;
  const int w    = tid >> 6;
  const int lane = tid & 63;
  const int l15  = lane & 15;
  const int g    = lane >> 4;  // 16-lane group 0..3

  const int b   = blockIdx.x >> 7;
  const int q0  = (blockIdx.x & 127) << 4;
  const int wk0 = w << 9;

  char* swave = (char*)s_lds + w * (QB * 512 * 4);

  // Q fragments (A-layout: row=l15, k=g*8+j): contiguous 16B bf16 loads
  const unsigned short* qptr = qb + ((size_t)(b * SEQ + q0 + l15)) * HD + g * 8;
  const short8 qf0 = *(const short8*)(qptr);
  const short8 qf1 = *(const short8*)(qptr + 32);

  // ---- Phase A: S = QK^T/8 + mask (masked-fill) -> fp32 logits in LDS ----
  const unsigned short* kbase = kb + ((size_t)(b * SEQ + wk0 + l15)) * HD + g * 8;
  const size_t mbase = ((size_t)(b) * SEQ + q0 + g * 4) * (size_t)SEQ + wk0 + l15;

  float  mbuf[4][4];   // 4-deep mask prefetch (D-layout: row=g*4+r, col=l15)
  short8 kbuf[4][2];   // 4-deep K fragment prefetch

#pragma unroll
  for (int i = 0; i < 4; ++i) {
    const unsigned short* kp = kbase + (size_t)i * (16 * HD);
    kbuf[i][0] = *(const short8*)(kp);
    kbuf[i][1] = *(const short8*)(kp + 32);
#pragma unroll
    for (int r = 0; r < 4; ++r)
      mbuf[i][r] = __builtin_nontemporal_load(mask + mbase + (size_t)r * SEQ + i * 16);
  }

  for (int t0 = 0; t0 < 32; t0 += 4) {
#pragma unroll
    for (int u = 0; u < 4; ++u) {
      const int t = t0 + u;
      f32x4 acc = {0.f, 0.f, 0.f, 0.f};
      acc = __builtin_amdgcn_mfma_f32_16x16x32_bf16(qf0, kbuf[u][0], acc, 0, 0, 0);
      acc = __builtin_amdgcn_mfma_f32_16x16x32_bf16(qf1, kbuf[u][1], acc, 0, 0, 0);
      float mv[4];
#pragma unroll
      for (int r = 0; r < 4; ++r) mv[r] = mbuf[u][r];
      if (t + 4 < 32) {  // refill pipeline slot (4 tiles ahead)
        const unsigned short* kp = kbase + (size_t)(t + 4) * (16 * HD);
        kbuf[u][0] = *(const short8*)(kp);
        kbuf[u][1] = *(const short8*)(kp + 32);
#pragma unroll
        for (int r = 0; r < 4; ++r)
          mbuf[u][r] = __builtin_nontemporal_load(mask + mbase + (size_t)r * SEQ + (t + 4) * 16);
      }
#pragma unroll
      for (int r = 0; r < 4; ++r) {
        const int row  = g * 4 + r;                 // q-row in tile (D-layout)
        const float s  = (mv[r] < 0.f) ? NEG : fmaf(acc[r], 0.125f, mv[r]);
        const int byte = row * 2048 + (((t * 16 + l15) * 4) ^ ((row & 7) << 4));
        *(float*)(swave + byte) = s;
      }
    }
  }

  __syncthreads();

  // ---- Phase A2: softmax stats. Lane owns row R=l15, 8 k's per chunk ----
  const int R       = l15;
  const int swz     = (R & 7) << 4;
  const int rowbase = R * 2048;

  float mw = -3.0e38f;
#pragma unroll
  for (int ck = 0; ck < 16; ++ck) {
    const int off = ck * 128 + g * 32;
    f32x4 a = *(const f32x4*)(swave + rowbase + (off ^ swz));
    f32x4 c = *(const f32x4*)(swave + rowbase + ((off + 16) ^ swz));
    mw = fmaxf(mw, fmaxf(fmaxf(a[0], a[1]), fmaxf(a[2], a[3])));
    mw = fmaxf(mw, fmaxf(fmaxf(c[0], c[1]), fmaxf(c[2], c[3])));
  }
  mw = fmaxf(mw, __shfl_xor(mw, 16));
  mw = fmaxf(mw, __shfl_xor(mw, 32));

  float lw = 0.f;
#pragma unroll
  for (int ck = 0; ck < 16; ++ck) {
    const int off = ck * 128 + g * 32;
    f32x4 a = *(const f32x4*)(swave + rowbase + (off ^ swz));
    f32x4 c = *(const f32x4*)(swave + rowbase + ((off + 16) ^ swz));
    lw += __expf(a[0] - mw); lw += __expf(a[1] - mw);
    lw += __expf(a[2] - mw); lw += __expf(a[3] - mw);
    lw += __expf(c[0] - mw); lw += __expf(c[1] - mw);
    lw += __expf(c[2] - mw); lw += __expf(c[3] - mw);
  }
  lw += __shfl_xor(lw, 16);
  lw += __shfl_xor(lw, 32);

  if (lane < 16) { stat_m[w][lane] = mw; stat_l[w][lane] = lw; }
  __syncthreads();

  float mg = -3.0e38f;
#pragma unroll
  for (int ww = 0; ww < 4; ++ww) mg = fmaxf(mg, stat_m[ww][R]);
  float lg = 0.f;
#pragma unroll
  for (int ww = 0; ww < 4; ++ww) lg += stat_l[ww][R] * __expf(stat_m[ww][R] - mg);
  const float rl = 1.0f / lg;

  // ---- Pass B: attn = exp(s-mg)/lg -> HBM (NT), and PV via MFMA ----
  f32x4 oacc[4];
#pragma unroll
  for (int nt = 0; nt < 4; ++nt) oacc[nt] = (f32x4){0.f, 0.f, 0.f, 0.f};

  float* attn_base = attn + ((size_t)(b * SEQ + q0 + R)) * (size_t)SEQ + wk0 + g * 8;
  const unsigned short* vbase = vt + ((size_t)(b * HD + l15)) * SEQ + wk0 + g * 8;

  short8 vb0[4], vb1[4];
#pragma unroll
  for (int nt = 0; nt < 4; ++nt)
    vb0[nt] = *(const short8*)(vbase + (size_t)nt * 16 * SEQ);

  auto pv_step = [&](const int ck, short8* vcur, short8* vnext) {
    if (ck + 1 < 16) {  // prefetch next chunk's V^T fragments (L2-resident)
#pragma unroll
      for (int nt = 0; nt < 4; ++nt)
        vnext[nt] = *(const short8*)(vbase + (size_t)nt * 16 * SEQ + (ck + 1) * 32);
    }
    const int off = ck * 128 + g * 32;
    f32x4 a = *(const f32x4*)(swave + rowbase + (off ^ swz));
    f32x4 c = *(const f32x4*)(swave + rowbase + ((off + 16) ^ swz));
    f32x4 p0, p1;
    p0[0] = __expf(a[0] - mg) * rl; p0[1] = __expf(a[1] - mg) * rl;
    p0[2] = __expf(a[2] - mg) * rl; p0[3] = __expf(a[3] - mg) * rl;
    p1[0] = __expf(c[0] - mg) * rl; p1[1] = __expf(c[1] - mg) * rl;
    p1[2] = __expf(c[2] - mg) * rl; p1[3] = __expf(c[3] - mg) * rl;
    __builtin_nontemporal_store(p0, (f32x4*)(attn_base + ck * 32));
    __builtin_nontemporal_store(p1, (f32x4*)(attn_base + ck * 32 + 4));
    short8 pf;  // PV A-fragment: row=l15(q), k=g*8+j — exactly our 8 p's
    pf[0] = (short)f2bf(p0[0]); pf[1] = (short)f2bf(p0[1]);
    pf[2] = (short)f2bf(p0[2]); pf[3] = (short)f2bf(p0[3]);
    pf[4] = (short)f2bf(p1[0]); pf[5] = (short)f2bf(p1[1]);
    pf[6] = (short)f2bf(p1[2]); pf[7] = (short)f2bf(p1[3]);
#pragma unroll
    for (int nt = 0; nt < 4; ++nt)
      oacc[nt] = __builtin_amdgcn_mfma_f32_16x16x32_bf16(pf, vcur[nt], oacc[nt], 0, 0, 0);
  };

  for (int ck0 = 0; ck0 < 16; ck0 += 2) {  // manual 2-buffer (rule #20: static idx)
    pv_step(ck0,     vb0, vb1);
    pv_step(ck0 + 1, vb1, vb0);
  }

  // ---- cross-wave partial-O reduction (reuse own LDS region) ----
#pragma unroll
  for (int nt = 0; nt < 4; ++nt) {
#pragma unroll
    for (int r = 0; r < 4; ++r) {
      const int row = g * 4 + r;
      ((float*)swave)[row * 64 + nt * 16 + l15] = oacc[nt][r];
    }
  }
  __syncthreads();

  {
    const int d  = tid & 63;
    const int r0 = tid >> 6;
#pragma unroll
    for (int i = 0; i < 4; ++i) {
      const int row = r0 + i * 4;
      float s = 0.f;
#pragma unroll
      for (int ww = 0; ww < 4; ++ww)
        s += s_lds[ww * (QB * 512) + row * 64 + d];
      out[((size_t)(b * SEQ + q0 + row)) * HD + d] = s;
    }
  }
}

extern "C" void kernel_launch(void* const* d_in, const int* in_sizes, int n_in,
                              void* d_out, int out_size, void* d_ws, size_t ws_size,
                              hipStream_t stream) {
  const float* q    = (const float*)d_in[0];
  const float* k    = (const float*)d_in[1];
  const float* v    = (const float*)d_in[2];
  const float* mask = (const float*)d_in[3];

  float* out  = (float*)d_out;
  float* attn = out + (size_t)BATCH * SEQ * HD;  // tuple: (output, attn)

  // workspace: bf16 Q (16MB) | bf16 K (16MB) | bf16 V^T (16MB) = 48MB
  const size_t nqk = (size_t)BATCH * SEQ * HD;
  unsigned short* qb = (unsigned short*)d_ws;
  unsigned short* kb = qb + nqk;
  unsigned short* vt = kb + nqk;

  const int n4 = (int)(nqk / 4);
  cvt_bf16_kernel<<<dim3((n4 + 255) / 256), dim3(256), 0, stream>>>(q, qb, n4);
  cvt_bf16_kernel<<<dim3((n4 + 255) / 256), dim3(256), 0, stream>>>(k, kb, n4);
  vtrans_kernel<<<dim3(BATCH * (SEQ / 64)), dim3(256), 0, stream>>>(v, vt);
  attn_kernel<<<dim3(BATCH * (SEQ / QB)), dim3(256), 0, stream>>>(qb, kb, vt, mask, out, attn);
}

// Round 3
// 882.835 us; speedup vs baseline: 1.0591x; 1.0591x over previous
//
#include <hip/hip_runtime.h>
#include <stdint.h>
#include <stddef.h>

// ScaledDotProductAttention: B=64, Lq=Lk=2048, D=64, fp32 in/out.
// out tuple = (output [64][2048][64], attn [64][2048][2048]) concat in d_out.
// R2b: logits live in REGISTERS as packed fp16 (64 VGPRs/lane) instead of a
// 128KB LDS buffer; small 32KB LDS bounce per 128-col chunk for the
// transpose into coalesced attn stores + MFMA-A fragments. 3 WG/CU target.

typedef __attribute__((ext_vector_type(4))) float f32x4;
typedef __attribute__((ext_vector_type(8))) short short8;
typedef __attribute__((ext_vector_type(4))) unsigned short ushort4v;
typedef __attribute__((ext_vector_type(8))) unsigned short ushort8v;
typedef __fp16 f16x2 __attribute__((ext_vector_type(2)));

static constexpr int BATCH = 64;
static constexpr int SEQ   = 2048;   // lq == lk
static constexpr int HD    = 64;     // head dim
static constexpr int QB    = 16;     // q rows per workgroup
static constexpr float NEGH = -60000.0f;  // "-inf" that survives fp16

__device__ __forceinline__ unsigned short f2bf(float f) {
  unsigned int u = __builtin_bit_cast(unsigned int, f);
  u += 0x7fffu + ((u >> 16) & 1u);
  return (unsigned short)(u >> 16);
}

// ---------------- pre-pass: fp32 -> bf16 flat convert ----------------
__global__ void cvt_bf16_kernel(const float* __restrict__ in,
                                unsigned short* __restrict__ out, int n4) {
  int i = blockIdx.x * blockDim.x + threadIdx.x;
  if (i >= n4) return;
  f32x4 v = *(const f32x4*)(in + (size_t)i * 4);
  ushort4v o;
  o[0] = f2bf(v[0]); o[1] = f2bf(v[1]); o[2] = f2bf(v[2]); o[3] = f2bf(v[3]);
  *(ushort4v*)(out + (size_t)i * 4) = o;
}

// ---------------- pre-pass: V [b][k][d] -> VT bf16 [b][d][k] ----------------
__global__ void vtrans_kernel(const float* __restrict__ v,
                              unsigned short* __restrict__ vt) {
  __shared__ float tile[64][65];
  const int b  = blockIdx.x >> 5;
  const int k0 = (blockIdx.x & 31) << 6;
  const int t  = threadIdx.x;
  const int kk = t >> 4;
  const int d4 = (t & 15) << 2;
#pragma unroll
  for (int i = 0; i < 4; ++i) {
    f32x4 val = *(const f32x4*)(v + ((size_t)(b * SEQ + k0 + kk + 16 * i)) * HD + d4);
    tile[kk + 16 * i][d4 + 0] = val[0];
    tile[kk + 16 * i][d4 + 1] = val[1];
    tile[kk + 16 * i][d4 + 2] = val[2];
    tile[kk + 16 * i][d4 + 3] = val[3];
  }
  __syncthreads();
  const int d  = t >> 2;
  const int ks = (t & 3) << 4;
  ushort8v o0, o1;
#pragma unroll
  for (int j = 0; j < 8; ++j) o0[j] = f2bf(tile[ks + j][d]);
#pragma unroll
  for (int j = 0; j < 8; ++j) o1[j] = f2bf(tile[ks + 8 + j][d]);
  unsigned short* dst = vt + ((size_t)(b * HD + d)) * SEQ + k0 + ks;
  *(ushort8v*)(dst)     = o0;
  *(ushort8v*)(dst + 8) = o1;
}

// ---------------- main fused attention ----------------
// grid: 64 batches x 128 q-tiles; block 256 (4 waves); wave w owns k-range
// [w*512, w*512+512). Logits packed fp16 in registers (f16x2 ph[64]).
__global__ __launch_bounds__(256, 3) void attn_kernel(
    const unsigned short* __restrict__ qb,
    const unsigned short* __restrict__ kb,
    const unsigned short* __restrict__ vt,
    const float* __restrict__ mask,
    float* __restrict__ out,
    float* __restrict__ attn) {
  __shared__ float s_chunk[4 * 16 * 128];  // 32KB: per-wave 16x128 f32 bounce
  __shared__ float stat_m[4][16];
  __shared__ float stat_l[4][16];

  const int tid  = threadIdx.x;
  const int w    = tid >> 6;
  const int lane = tid & 63;
  const int l15  = lane & 15;
  const int g    = lane >> 4;  // 16-lane group 0..3

  const int b   = blockIdx.x >> 7;
  const int q0  = (blockIdx.x & 127) << 4;
  const int wk0 = w << 9;

  char* lds = (char*)s_chunk;
  const int wbase = w * 8192;  // per-wave 8KB bounce region

  // Q fragments (A-layout: row=l15, k=g*8+j)
  const unsigned short* qptr = qb + ((size_t)(b * SEQ + q0 + l15)) * HD + g * 8;
  const short8 qf0 = *(const short8*)(qptr);
  const short8 qf1 = *(const short8*)(qptr + 32);

  const unsigned short* kbase = kb + ((size_t)(b * SEQ + wk0 + l15)) * HD + g * 8;
  const size_t mbase = ((size_t)(b) * SEQ + q0 + g * 4) * (size_t)SEQ + wk0 + l15;

  // ---- Phase A: S = QK^T/8 + mask -> packed fp16 registers + running max ----
  f16x2  ph[64];       // 32 tiles x 4 rows, rows (r0,r1) and (r2,r3) packed
  float  mbuf[4][4];   // 4-deep mask prefetch
  short8 kbuf[2][2];   // 2-deep K prefetch (L2-resident)
  float  mrow[4] = {-3.0e38f, -3.0e38f, -3.0e38f, -3.0e38f};

#pragma unroll
  for (int i = 0; i < 2; ++i) {
    const unsigned short* kp = kbase + (size_t)i * (16 * HD);
    kbuf[i][0] = *(const short8*)(kp);
    kbuf[i][1] = *(const short8*)(kp + 32);
  }
#pragma unroll
  for (int i = 0; i < 4; ++i)
#pragma unroll
    for (int r = 0; r < 4; ++r)
      mbuf[i][r] = __builtin_nontemporal_load(mask + mbase + (size_t)r * SEQ + i * 16);

#pragma unroll
  for (int t = 0; t < 32; ++t) {
    f32x4 acc = {0.f, 0.f, 0.f, 0.f};
    acc = __builtin_amdgcn_mfma_f32_16x16x32_bf16(qf0, kbuf[t & 1][0], acc, 0, 0, 0);
    acc = __builtin_amdgcn_mfma_f32_16x16x32_bf16(qf1, kbuf[t & 1][1], acc, 0, 0, 0);
    if (t + 2 < 32) {
      const unsigned short* kp = kbase + (size_t)(t + 2) * (16 * HD);
      kbuf[t & 1][0] = *(const short8*)(kp);
      kbuf[t & 1][1] = *(const short8*)(kp + 32);
    }
    float s[4];
#pragma unroll
    for (int r = 0; r < 4; ++r) {
      const float mv = mbuf[t & 3][r];
      s[r] = (mv < 0.f) ? NEGH : fmaf(acc[r], 0.125f, mv);
      mrow[r] = fmaxf(mrow[r], s[r]);
    }
    if (t + 4 < 32) {
#pragma unroll
      for (int r = 0; r < 4; ++r)
        mbuf[t & 3][r] = __builtin_nontemporal_load(mask + mbase + (size_t)r * SEQ + (t + 4) * 16);
    }
    ph[2 * t]     = __builtin_amdgcn_cvt_pkrtz(s[0], s[1]);
    ph[2 * t + 1] = __builtin_amdgcn_cvt_pkrtz(s[2], s[3]);
  }

  // lane-reduce row max across the 16 lanes sharing this g-group
#pragma unroll
  for (int r = 0; r < 4; ++r) {
    mrow[r] = fmaxf(mrow[r], __shfl_xor(mrow[r], 1));
    mrow[r] = fmaxf(mrow[r], __shfl_xor(mrow[r], 2));
    mrow[r] = fmaxf(mrow[r], __shfl_xor(mrow[r], 4));
    mrow[r] = fmaxf(mrow[r], __shfl_xor(mrow[r], 8));
  }

  // ---- Phase A2: e = exp(s - mrow), sum, repack e over s ----
  float lw[4] = {0.f, 0.f, 0.f, 0.f};
#pragma unroll
  for (int t = 0; t < 32; ++t) {
    f16x2 h0 = ph[2 * t], h1 = ph[2 * t + 1];
    float e0 = __expf((float)h0[0] - mrow[0]);
    float e1 = __expf((float)h0[1] - mrow[1]);
    float e2 = __expf((float)h1[0] - mrow[2]);
    float e3 = __expf((float)h1[1] - mrow[3]);
    lw[0] += e0; lw[1] += e1; lw[2] += e2; lw[3] += e3;
    ph[2 * t]     = __builtin_amdgcn_cvt_pkrtz(e0, e1);
    ph[2 * t + 1] = __builtin_amdgcn_cvt_pkrtz(e2, e3);
  }
#pragma unroll
  for (int r = 0; r < 4; ++r) {
    lw[r] += __shfl_xor(lw[r], 1);
    lw[r] += __shfl_xor(lw[r], 2);
    lw[r] += __shfl_xor(lw[r], 4);
    lw[r] += __shfl_xor(lw[r], 8);
  }

  if (l15 == 0) {
#pragma unroll
    for (int r = 0; r < 4; ++r) {
      stat_m[w][g * 4 + r] = mrow[r];
      stat_l[w][g * 4 + r] = lw[r];
    }
  }
  __syncthreads();

  // cross-wave merge -> per-row scale = exp(m_wave - m_glob) / l_glob
  float scale[4];
#pragma unroll
  for (int r = 0; r < 4; ++r) {
    const int row = g * 4 + r;
    float mg = -3.0e38f;
#pragma unroll
    for (int ww = 0; ww < 4; ++ww) mg = fmaxf(mg, stat_m[ww][row]);
    float lg = 0.f;
#pragma unroll
    for (int ww = 0; ww < 4; ++ww) lg += stat_l[ww][row] * __expf(stat_m[ww][row] - mg);
    scale[r] = __expf(mrow[r] - mg) / lg;
  }

  // ---- Phase B: chunked LDS transpose -> attn stores + PV MFMA ----
  f32x4 oacc[4];
#pragma unroll
  for (int nt = 0; nt < 4; ++nt) oacc[nt] = (f32x4){0.f, 0.f, 0.f, 0.f};

  float* attn_base = attn + ((size_t)(b * SEQ + q0 + l15)) * (size_t)SEQ + wk0;
  const unsigned short* vbase = vt + ((size_t)(b * HD + l15)) * SEQ + wk0 + g * 8;

  short8 vbuf[2][4];
#pragma unroll
  for (int nt = 0; nt < 4; ++nt)
    vbuf[0][nt] = *(const short8*)(vbase + (size_t)nt * 16 * SEQ);

  const int rbase = wbase + l15 * 512;         // read row base (row = l15)
  const int swzR  = (l15 & 7) << 4;

#pragma unroll
  for (int c = 0; c < 4; ++c) {
    // unpack 8 tiles, scale, write D-layout (row=g*4+r, col=tt*16+l15) swizzled
#pragma unroll
    for (int tt = 0; tt < 8; ++tt) {
      const int t = 8 * c + tt;
      f16x2 h0 = ph[2 * t], h1 = ph[2 * t + 1];
      float p[4];
      p[0] = (float)h0[0] * scale[0];
      p[1] = (float)h0[1] * scale[1];
      p[2] = (float)h1[0] * scale[2];
      p[3] = (float)h1[1] * scale[3];
      const int colb = (tt * 16 + l15) * 4;
#pragma unroll
      for (int r = 0; r < 4; ++r) {
        const int row = g * 4 + r;
        *(float*)(lds + wbase + row * 512 + (colb ^ ((row & 7) << 4))) = p[r];
      }
    }
    __syncthreads();

    // read A-layout (row=l15, k=g*8+j), store attn coalesced, PV MFMA
#pragma unroll
    for (int ck = 0; ck < 4; ++ck) {
      const int kidx = c * 4 + ck;  // 32-col unit within the wave's 512
      if (kidx + 1 < 16) {
#pragma unroll
        for (int nt = 0; nt < 4; ++nt)
          vbuf[(kidx + 1) & 1][nt] =
              *(const short8*)(vbase + (size_t)nt * 16 * SEQ + (kidx + 1) * 32);
      }
      const int d0 = (ck * 32 + g * 8) * 4;  // byte col offset in 512B row
      f32x4 a  = *(const f32x4*)(lds + rbase + (d0 ^ swzR));
      f32x4 cc = *(const f32x4*)(lds + rbase + ((d0 + 16) ^ swzR));
      *(f32x4*)(attn_base + kidx * 32 + g * 8)     = a;
      *(f32x4*)(attn_base + kidx * 32 + g * 8 + 4) = cc;
      short8 pf;
      pf[0] = (short)f2bf(a[0]);  pf[1] = (short)f2bf(a[1]);
      pf[2] = (short)f2bf(a[2]);  pf[3] = (short)f2bf(a[3]);
      pf[4] = (short)f2bf(cc[0]); pf[5] = (short)f2bf(cc[1]);
      pf[6] = (short)f2bf(cc[2]); pf[7] = (short)f2bf(cc[3]);
#pragma unroll
      for (int nt = 0; nt < 4; ++nt)
        oacc[nt] = __builtin_amdgcn_mfma_f32_16x16x32_bf16(pf, vbuf[kidx & 1][nt], oacc[nt], 0, 0, 0);
    }
    __syncthreads();
  }

  // ---- cross-wave partial-O reduction (reuse bounce region) ----
#pragma unroll
  for (int nt = 0; nt < 4; ++nt) {
#pragma unroll
    for (int r = 0; r < 4; ++r) {
      const int row = g * 4 + r;
      s_chunk[w * 2048 + row * 64 + nt * 16 + l15] = oacc[nt][r];
    }
  }
  __syncthreads();

  {
    const int d  = tid & 63;
    const int r0 = tid >> 6;
#pragma unroll
    for (int i = 0; i < 4; ++i) {
      const int row = r0 + i * 4;
      float s = 0.f;
#pragma unroll
      for (int ww = 0; ww < 4; ++ww)
        s += s_chunk[ww * 2048 + row * 64 + d];
      out[((size_t)(b * SEQ + q0 + row)) * HD + d] = s;
    }
  }
}

extern "C" void kernel_launch(void* const* d_in, const int* in_sizes, int n_in,
                              void* d_out, int out_size, void* d_ws, size_t ws_size,
                              hipStream_t stream) {
  const float* q    = (const float*)d_in[0];
  const float* k    = (const float*)d_in[1];
  const float* v    = (const float*)d_in[2];
  const float* mask = (const float*)d_in[3];

  float* out  = (float*)d_out;
  float* attn = out + (size_t)BATCH * SEQ * HD;  // tuple: (output, attn)

  const size_t nqk = (size_t)BATCH * SEQ * HD;
  unsigned short* qb = (unsigned short*)d_ws;
  unsigned short* kb = qb + nqk;
  unsigned short* vt = kb + nqk;

  const int n4 = (int)(nqk / 4);
  cvt_bf16_kernel<<<dim3((n4 + 255) / 256), dim3(256), 0, stream>>>(q, qb, n4);
  cvt_bf16_kernel<<<dim3((n4 + 255) / 256), dim3(256), 0, stream>>>(k, kb, n4);
  vtrans_kernel<<<dim3(BATCH * (SEQ / 64)), dim3(256), 0, stream>>>(v, vt);
  attn_kernel<<<dim3(BATCH * (SEQ / QB)), dim3(256), 0, stream>>>(qb, kb, vt, mask, out, attn);
}

// Round 4
// 870.473 us; speedup vs baseline: 1.0741x; 1.0142x over previous
//
#include <hip/hip_runtime.h>
#include <stdint.h>
#include <stddef.h>

// ScaledDotProductAttention: B=64, Lq=Lk=2048, D=64, fp32 in/out.
// out tuple = (output [64][2048][64], attn [64][2048][2048]) concat in d_out.
// R4: same structure as R3 (register-resident fp16 logits, 32KB LDS bounce),
// but __launch_bounds__(256,2): R3's (256,3) capped VGPRs at 84 and spilled
// the ph[64] logit array to scratch (the real reason occupancy didn't help).
// 2 WG/CU with ~200 VGPRs and zero spills.

typedef __attribute__((ext_vector_type(4))) float f32x4;
typedef __attribute__((ext_vector_type(8))) short short8;
typedef __attribute__((ext_vector_type(4))) unsigned short ushort4v;
typedef __attribute__((ext_vector_type(8))) unsigned short ushort8v;
typedef __fp16 f16x2 __attribute__((ext_vector_type(2)));

static constexpr int BATCH = 64;
static constexpr int SEQ   = 2048;   // lq == lk
static constexpr int HD    = 64;     // head dim
static constexpr int QB    = 16;     // q rows per workgroup
static constexpr float NEGH = -60000.0f;  // "-inf" that survives fp16

__device__ __forceinline__ unsigned short f2bf(float f) {
  unsigned int u = __builtin_bit_cast(unsigned int, f);
  u += 0x7fffu + ((u >> 16) & 1u);
  return (unsigned short)(u >> 16);
}

// ---------------- pre-pass: fp32 -> bf16 flat convert ----------------
__global__ void cvt_bf16_kernel(const float* __restrict__ in,
                                unsigned short* __restrict__ out, int n4) {
  int i = blockIdx.x * blockDim.x + threadIdx.x;
  if (i >= n4) return;
  f32x4 v = *(const f32x4*)(in + (size_t)i * 4);
  ushort4v o;
  o[0] = f2bf(v[0]); o[1] = f2bf(v[1]); o[2] = f2bf(v[2]); o[3] = f2bf(v[3]);
  *(ushort4v*)(out + (size_t)i * 4) = o;
}

// ---------------- pre-pass: V [b][k][d] -> VT bf16 [b][d][k] ----------------
__global__ void vtrans_kernel(const float* __restrict__ v,
                              unsigned short* __restrict__ vt) {
  __shared__ float tile[64][65];
  const int b  = blockIdx.x >> 5;
  const int k0 = (blockIdx.x & 31) << 6;
  const int t  = threadIdx.x;
  const int kk = t >> 4;
  const int d4 = (t & 15) << 2;
#pragma unroll
  for (int i = 0; i < 4; ++i) {
    f32x4 val = *(const f32x4*)(v + ((size_t)(b * SEQ + k0 + kk + 16 * i)) * HD + d4);
    tile[kk + 16 * i][d4 + 0] = val[0];
    tile[kk + 16 * i][d4 + 1] = val[1];
    tile[kk + 16 * i][d4 + 2] = val[2];
    tile[kk + 16 * i][d4 + 3] = val[3];
  }
  __syncthreads();
  const int d  = t >> 2;
  const int ks = (t & 3) << 4;
  ushort8v o0, o1;
#pragma unroll
  for (int j = 0; j < 8; ++j) o0[j] = f2bf(tile[ks + j][d]);
#pragma unroll
  for (int j = 0; j < 8; ++j) o1[j] = f2bf(tile[ks + 8 + j][d]);
  unsigned short* dst = vt + ((size_t)(b * HD + d)) * SEQ + k0 + ks;
  *(ushort8v*)(dst)     = o0;
  *(ushort8v*)(dst + 8) = o1;
}

// ---------------- main fused attention ----------------
// grid: 64 batches x 128 q-tiles; block 256 (4 waves); wave w owns k-range
// [w*512, w*512+512). Logits packed fp16 in registers (f16x2 ph[64]).
__global__ __launch_bounds__(256, 2) void attn_kernel(
    const unsigned short* __restrict__ qb,
    const unsigned short* __restrict__ kb,
    const unsigned short* __restrict__ vt,
    const float* __restrict__ mask,
    float* __restrict__ out,
    float* __restrict__ attn) {
  __shared__ float s_chunk[4 * 16 * 128];  // 32KB: per-wave 16x128 f32 bounce
  __shared__ float stat_m[4][16];
  __shared__ float stat_l[4][16];

  const int tid  = threadIdx.x;
  const int w    = tid >> 6;
  const int lane = tid & 63;
  const int l15  = lane & 15;
  const int g    = lane >> 4;  // 16-lane group 0..3

  const int b   = blockIdx.x >> 7;
  const int q0  = (blockIdx.x & 127) << 4;
  const int wk0 = w << 9;

  char* lds = (char*)s_chunk;
  const int wbase = w * 8192;  // per-wave 8KB bounce region

  // Q fragments (A-layout: row=l15, k=g*8+j)
  const unsigned short* qptr = qb + ((size_t)(b * SEQ + q0 + l15)) * HD + g * 8;
  const short8 qf0 = *(const short8*)(qptr);
  const short8 qf1 = *(const short8*)(qptr + 32);

  const unsigned short* kbase = kb + ((size_t)(b * SEQ + wk0 + l15)) * HD + g * 8;
  const size_t mbase = ((size_t)(b) * SEQ + q0 + g * 4) * (size_t)SEQ + wk0 + l15;

  // ---- Phase A: S = QK^T/8 + mask -> packed fp16 registers + running max ----
  f16x2  ph[64];       // 32 tiles x 4 rows, rows (r0,r1) and (r2,r3) packed
  float  mbuf[4][4];   // 4-deep mask prefetch
  short8 kbuf[2][2];   // 2-deep K prefetch (L2-resident)
  float  mrow[4] = {-3.0e38f, -3.0e38f, -3.0e38f, -3.0e38f};

#pragma unroll
  for (int i = 0; i < 2; ++i) {
    const unsigned short* kp = kbase + (size_t)i * (16 * HD);
    kbuf[i][0] = *(const short8*)(kp);
    kbuf[i][1] = *(const short8*)(kp + 32);
  }
#pragma unroll
  for (int i = 0; i < 4; ++i)
#pragma unroll
    for (int r = 0; r < 4; ++r)
      mbuf[i][r] = __builtin_nontemporal_load(mask + mbase + (size_t)r * SEQ + i * 16);

#pragma unroll
  for (int t = 0; t < 32; ++t) {
    f32x4 acc = {0.f, 0.f, 0.f, 0.f};
    acc = __builtin_amdgcn_mfma_f32_16x16x32_bf16(qf0, kbuf[t & 1][0], acc, 0, 0, 0);
    acc = __builtin_amdgcn_mfma_f32_16x16x32_bf16(qf1, kbuf[t & 1][1], acc, 0, 0, 0);
    if (t + 2 < 32) {
      const unsigned short* kp = kbase + (size_t)(t + 2) * (16 * HD);
      kbuf[t & 1][0] = *(const short8*)(kp);
      kbuf[t & 1][1] = *(const short8*)(kp + 32);
    }
    float s[4];
#pragma unroll
    for (int r = 0; r < 4; ++r) {
      const float mv = mbuf[t & 3][r];
      s[r] = (mv < 0.f) ? NEGH : fmaf(acc[r], 0.125f, mv);
      mrow[r] = fmaxf(mrow[r], s[r]);
    }
    if (t + 4 < 32) {
#pragma unroll
      for (int r = 0; r < 4; ++r)
        mbuf[t & 3][r] = __builtin_nontemporal_load(mask + mbase + (size_t)r * SEQ + (t + 4) * 16);
    }
    ph[2 * t]     = __builtin_amdgcn_cvt_pkrtz(s[0], s[1]);
    ph[2 * t + 1] = __builtin_amdgcn_cvt_pkrtz(s[2], s[3]);
  }

  // lane-reduce row max across the 16 lanes sharing this g-group
#pragma unroll
  for (int r = 0; r < 4; ++r) {
    mrow[r] = fmaxf(mrow[r], __shfl_xor(mrow[r], 1));
    mrow[r] = fmaxf(mrow[r], __shfl_xor(mrow[r], 2));
    mrow[r] = fmaxf(mrow[r], __shfl_xor(mrow[r], 4));
    mrow[r] = fmaxf(mrow[r], __shfl_xor(mrow[r], 8));
  }

  // ---- Phase A2: e = exp(s - mrow), sum, repack e over s ----
  float lw[4] = {0.f, 0.f, 0.f, 0.f};
#pragma unroll
  for (int t = 0; t < 32; ++t) {
    f16x2 h0 = ph[2 * t], h1 = ph[2 * t + 1];
    float e0 = __expf((float)h0[0] - mrow[0]);
    float e1 = __expf((float)h0[1] - mrow[1]);
    float e2 = __expf((float)h1[0] - mrow[2]);
    float e3 = __expf((float)h1[1] - mrow[3]);
    lw[0] += e0; lw[1] += e1; lw[2] += e2; lw[3] += e3;
    ph[2 * t]     = __builtin_amdgcn_cvt_pkrtz(e0, e1);
    ph[2 * t + 1] = __builtin_amdgcn_cvt_pkrtz(e2, e3);
  }
#pragma unroll
  for (int r = 0; r < 4; ++r) {
    lw[r] += __shfl_xor(lw[r], 1);
    lw[r] += __shfl_xor(lw[r], 2);
    lw[r] += __shfl_xor(lw[r], 4);
    lw[r] += __shfl_xor(lw[r], 8);
  }

  if (l15 == 0) {
#pragma unroll
    for (int r = 0; r < 4; ++r) {
      stat_m[w][g * 4 + r] = mrow[r];
      stat_l[w][g * 4 + r] = lw[r];
    }
  }
  __syncthreads();

  // cross-wave merge -> per-row scale = exp(m_wave - m_glob) / l_glob
  float scale[4];
#pragma unroll
  for (int r = 0; r < 4; ++r) {
    const int row = g * 4 + r;
    float mg = -3.0e38f;
#pragma unroll
    for (int ww = 0; ww < 4; ++ww) mg = fmaxf(mg, stat_m[ww][row]);
    float lg = 0.f;
#pragma unroll
    for (int ww = 0; ww < 4; ++ww) lg += stat_l[ww][row] * __expf(stat_m[ww][row] - mg);
    scale[r] = __expf(mrow[r] - mg) / lg;
  }

  // ---- Phase B: chunked LDS transpose -> attn stores + PV MFMA ----
  f32x4 oacc[4];
#pragma unroll
  for (int nt = 0; nt < 4; ++nt) oacc[nt] = (f32x4){0.f, 0.f, 0.f, 0.f};

  float* attn_base = attn + ((size_t)(b * SEQ + q0 + l15)) * (size_t)SEQ + wk0;
  const unsigned short* vbase = vt + ((size_t)(b * HD + l15)) * SEQ + wk0 + g * 8;

  short8 vbuf[2][4];
#pragma unroll
  for (int nt = 0; nt < 4; ++nt)
    vbuf[0][nt] = *(const short8*)(vbase + (size_t)nt * 16 * SEQ);

  const int rbase = wbase + l15 * 512;         // read row base (row = l15)
  const int swzR  = (l15 & 7) << 4;

#pragma unroll
  for (int c = 0; c < 4; ++c) {
    // unpack 8 tiles, scale, write D-layout (row=g*4+r, col=tt*16+l15) swizzled
#pragma unroll
    for (int tt = 0; tt < 8; ++tt) {
      const int t = 8 * c + tt;
      f16x2 h0 = ph[2 * t], h1 = ph[2 * t + 1];
      float p[4];
      p[0] = (float)h0[0] * scale[0];
      p[1] = (float)h0[1] * scale[1];
      p[2] = (float)h1[0] * scale[2];
      p[3] = (float)h1[1] * scale[3];
      const int colb = (tt * 16 + l15) * 4;
#pragma unroll
      for (int r = 0; r < 4; ++r) {
        const int row = g * 4 + r;
        *(float*)(lds + wbase + row * 512 + (colb ^ ((row & 7) << 4))) = p[r];
      }
    }
    __syncthreads();

    // read A-layout (row=l15, k=g*8+j), store attn coalesced, PV MFMA
#pragma unroll
    for (int ck = 0; ck < 4; ++ck) {
      const int kidx = c * 4 + ck;  // 32-col unit within the wave's 512
      if (kidx + 1 < 16) {
#pragma unroll
        for (int nt = 0; nt < 4; ++nt)
          vbuf[(kidx + 1) & 1][nt] =
              *(const short8*)(vbase + (size_t)nt * 16 * SEQ + (kidx + 1) * 32);
      }
      const int d0 = (ck * 32 + g * 8) * 4;  // byte col offset in 512B row
      f32x4 a  = *(const f32x4*)(lds + rbase + (d0 ^ swzR));
      f32x4 cc = *(const f32x4*)(lds + rbase + ((d0 + 16) ^ swzR));
      *(f32x4*)(attn_base + kidx * 32 + g * 8)     = a;
      *(f32x4*)(attn_base + kidx * 32 + g * 8 + 4) = cc;
      short8 pf;
      pf[0] = (short)f2bf(a[0]);  pf[1] = (short)f2bf(a[1]);
      pf[2] = (short)f2bf(a[2]);  pf[3] = (short)f2bf(a[3]);
      pf[4] = (short)f2bf(cc[0]); pf[5] = (short)f2bf(cc[1]);
      pf[6] = (short)f2bf(cc[2]); pf[7] = (short)f2bf(cc[3]);
#pragma unroll
      for (int nt = 0; nt < 4; ++nt)
        oacc[nt] = __builtin_amdgcn_mfma_f32_16x16x32_bf16(pf, vbuf[kidx & 1][nt], oacc[nt], 0, 0, 0);
    }
    __syncthreads();
  }

  // ---- cross-wave partial-O reduction (reuse bounce region) ----
#pragma unroll
  for (int nt = 0; nt < 4; ++nt) {
#pragma unroll
    for (int r = 0; r < 4; ++r) {
      const int row = g * 4 + r;
      s_chunk[w * 2048 + row * 64 + nt * 16 + l15] = oacc[nt][r];
    }
  }
  __syncthreads();

  {
    const int d  = tid & 63;
    const int r0 = tid >> 6;
#pragma unroll
    for (int i = 0; i < 4; ++i) {
      const int row = r0 + i * 4;
      float s = 0.f;
#pragma unroll
      for (int ww = 0; ww < 4; ++ww)
        s += s_chunk[ww * 2048 + row * 64 + d];
      out[((size_t)(b * SEQ + q0 + row)) * HD + d] = s;
    }
  }
}

extern "C" void kernel_launch(void* const* d_in, const int* in_sizes, int n_in,
                              void* d_out, int out_size, void* d_ws, size_t ws_size,
                              hipStream_t stream) {
  const float* q    = (const float*)d_in[0];
  const float* k    = (const float*)d_in[1];
  const float* v    = (const float*)d_in[2];
  const float* mask = (const float*)d_in[3];

  float* out  = (float*)d_out;
  float* attn = out + (size_t)BATCH * SEQ * HD;  // tuple: (output, attn)

  const size_t nqk = (size_t)BATCH * SEQ * HD;
  unsigned short* qb = (unsigned short*)d_ws;
  unsigned short* kb = qb + nqk;
  unsigned short* vt = kb + nqk;

  const int n4 = (int)(nqk / 4);
  cvt_bf16_kernel<<<dim3((n4 + 255) / 256), dim3(256), 0, stream>>>(q, qb, n4);
  cvt_bf16_kernel<<<dim3((n4 + 255) / 256), dim3(256), 0, stream>>>(k, kb, n4);
  vtrans_kernel<<<dim3(BATCH * (SEQ / 64)), dim3(256), 0, stream>>>(v, vt);
  attn_kernel<<<dim3(BATCH * (SEQ / QB)), dim3(256), 0, stream>>>(qb, kb, vt, mask, out, attn);
}